// Round 5
// baseline (301.642 us; speedup 1.0000x reference)
//
#include <hip/hip_runtime.h>
#include <hip/hip_bf16.h>

#define D_MODEL 1024
#define N_HEADS 16
#define HEAD_DIM 64
#define SEQ 2048
#define BATCH 2
#define INNER_DIM 4096
#define ROWS (BATCH*SEQ)   // 4096

using f32x4  = __attribute__((ext_vector_type(4))) float;
using bf16x8 = __attribute__((ext_vector_type(8))) short;   // 8 bf16 raw bits

__device__ __forceinline__ void gl_lds16(const void* g, void* l) {
  __builtin_amdgcn_global_load_lds(
      (const __attribute__((address_space(1))) void*)g,
      (__attribute__((address_space(3))) void*)l, 16, 0, 0);
}

__device__ __forceinline__ float bf2f(unsigned short u) {
  union { unsigned int i; float f; } v; v.i = ((unsigned int)u) << 16; return v.f;
}
__device__ __forceinline__ unsigned short f2bf(float f) {
  union { float f; unsigned int i; } v; v.f = f;
  unsigned int x = v.i;
  return (unsigned short)((x + 0x7fffu + ((x >> 16) & 1u)) >> 16);  // RTNE
}

__device__ __forceinline__ float exp2fast(float x) {
  return __builtin_amdgcn_exp2f(x);   // v_exp_f32
}

__device__ __forceinline__ float gelu_tanh(float x) {
  float x3 = x * x * x;
  float z = 0.7978845608028654f * (x + 0.044715f * x3);
  z = fminf(z, 15.0f);
  float e = __expf(2.0f * z);
  float th = (e - 1.0f) / (e + 1.0f);
  return 0.5f * x * (1.0f + th);
}

// ---------------- weight convert + transpose: in[K][N] f32 -> out[N][K] bf16 ----
__global__ void transpose_convert(const float* __restrict__ in,
                                  unsigned short* __restrict__ out,
                                  int K, int N) {
  __shared__ float tile[32][33];
  int n0 = blockIdx.x * 32, k0 = blockIdx.y * 32;
  int tx = threadIdx.x, ty = threadIdx.y;   // 32 x 8
#pragma unroll
  for (int i = 0; i < 4; i++)
    tile[ty + i * 8][tx] = in[(size_t)(k0 + ty + i * 8) * N + n0 + tx];
  __syncthreads();
#pragma unroll
  for (int i = 0; i < 4; i++)
    out[(size_t)(n0 + ty + i * 8) * K + k0 + tx] = f2bf(tile[tx][ty + i * 8]);
}

// ---------------- LayerNorm + adaLN modulation -> bf16 ------------------------
template<int SH_IDX, int SC_IDX>
__global__ void ln_mod_kernel(const float* __restrict__ x,
                              const float* __restrict__ lw,
                              const float* __restrict__ lb,
                              const float* __restrict__ sst,
                              const float* __restrict__ temb,
                              unsigned short* __restrict__ out) {
  int row = blockIdx.x;            // 0..4095
  int b = row >> 11;
  int t = threadIdx.x;             // 256
  const float* xr = x + (size_t)row * D_MODEL;
  float4 v = ((const float4*)xr)[t];
  float s = v.x + v.y + v.z + v.w;
  float s2 = v.x * v.x + v.y * v.y + v.z * v.z + v.w * v.w;
#pragma unroll
  for (int o = 1; o < 64; o <<= 1) { s += __shfl_xor(s, o); s2 += __shfl_xor(s2, o); }
  __shared__ float red[8];
  int wid = t >> 6, lane = t & 63;
  if (lane == 0) { red[wid] = s; red[4 + wid] = s2; }
  __syncthreads();
  s = red[0] + red[1] + red[2] + red[3];
  s2 = red[4] + red[5] + red[6] + red[7];
  float mu = s * (1.0f / D_MODEL);
  float var = s2 * (1.0f / D_MODEL) - mu * mu;
  float rs = rsqrtf(var + 1e-5f);
  int d0 = t * 4;
  float xv[4] = { v.x, v.y, v.z, v.w };
  ushort4 ov;
  unsigned short* po = (unsigned short*)&ov;
#pragma unroll
  for (int j = 0; j < 4; j++) {
    int d = d0 + j;
    float ln = (xv[j] - mu) * rs * lw[d] + lb[d];
    float sc = sst[SC_IDX * D_MODEL + d] + temb[b * 6 * D_MODEL + SC_IDX * D_MODEL + d];
    float sh = sst[SH_IDX * D_MODEL + d] + temb[b * 6 * D_MODEL + SH_IDX * D_MODEL + d];
    po[j] = f2bf(ln * (1.0f + sc) + sh);
  }
  *((ushort4*)(out + (size_t)row * D_MODEL + d0)) = ov;
}

// ---------------- GEMM: C[M,N] = A[M,K] @ Bt[N,K]^T + bias, fused epilogues ---
// Ring-of-4 LDS buffers: tile t+3 staged while computing t -> 3 tiles (~900cyc)
// of HBM latency in flight across barriers (counted vmcnt, never drained).
// EPI_QKV applies RoPE in the epilogue (paired cols via shfl_xor(v,1)).
enum { EPI_QKV = 0, EPI_RES = 1, EPI_GELU = 2, EPI_FINAL = 3 };

template<int EPI, int BMF>
__global__ __launch_bounds__(256, 2)
void gemm_kernel(const unsigned short* __restrict__ A,
                 const unsigned short* __restrict__ Bt,
                 const float* __restrict__ bias,
                 void* __restrict__ Cout,
                 int N, int K,
                 const float* __restrict__ sst,
                 const float* __restrict__ temb,
                 int g_idx,
                 const float* __restrict__ res,
                 const float* __restrict__ cosb,
                 const float* __restrict__ sinb) {
  constexpr int NBUF = 4;
  __shared__ unsigned short Alds[NBUF][BMF * 32 * 32];
  __shared__ unsigned short Blds[NBUF][128 * 32];
  const int t = threadIdx.x;
  const int w = t >> 6, l = t & 63;
  const int lg = l >> 4, ll = l & 15;
  const int wm = w >> 1, wn = w & 1;

  // T1: bijective XCD-chunked remap of the flattened block id (nwg % 8 == 0)
  const int nx = gridDim.x;
  const int nwg = nx * gridDim.y;
  const int lid = blockIdx.y * nx + blockIdx.x;
  const int nid = (lid & 7) * (nwg >> 3) + (lid >> 3);
  const int m0 = (nid / nx) * (BMF * 32), n0 = (nid % nx) * 128;

  f32x4 acc[BMF][4] = {};

  auto stage = [&](int k0, int buf) {
#pragma unroll
    for (int i = 0; i < BMF / 2; i++) {
      int c = i * 256 + t;
      int row = c >> 2, ch = c & 3;
      int chs = ch ^ ((row >> 1) & 3);
      gl_lds16(A + (size_t)(m0 + row) * K + k0 + chs * 8, (char*)&Alds[buf][0] + c * 16);
    }
#pragma unroll
    for (int i = 0; i < 2; i++) {
      int c = i * 256 + t;
      int row = c >> 2, ch = c & 3;
      int chs = ch ^ ((row >> 1) & 3);
      gl_lds16(Bt + (size_t)(n0 + row) * K + k0 + chs * 8, (char*)&Blds[buf][0] + c * 16);
    }
  };

  auto comp = [&](int buf) {
    asm volatile("" ::: "memory");
    bf16x8 af[BMF], bfr[4];
#pragma unroll
    for (int mf = 0; mf < BMF; mf++) {
      int row = wm * (BMF * 16) + mf * 16 + ll;
      int ch = lg ^ ((row >> 1) & 3);
      af[mf] = *(const bf16x8*)((const char*)&Alds[buf][0] + row * 64 + ch * 16);
    }
#pragma unroll
    for (int nf = 0; nf < 4; nf++) {
      int row = wn * 64 + nf * 16 + ll;
      int ch = lg ^ ((row >> 1) & 3);
      bfr[nf] = *(const bf16x8*)((const char*)&Blds[buf][0] + row * 64 + ch * 16);
    }
#pragma unroll
    for (int mf = 0; mf < BMF; mf++)
#pragma unroll
      for (int nf = 0; nf < 4; nf++)
        acc[mf][nf] = __builtin_amdgcn_mfma_f32_16x16x32_bf16(af[mf], bfr[nf], acc[mf][nf], 0, 0, 0);
    asm volatile("" ::: "memory");
  };

  const int nk = K >> 5;   // K/32, always >= 32
  stage(0, 0); stage(32, 1); stage(64, 2);
  int it = 0;
  for (; it + 3 < nk; ++it) {
    stage((it + 3) * 32, (it + 3) & 3);
    if constexpr (BMF == 4) asm volatile("s_waitcnt vmcnt(12)" ::: "memory");
    else                    asm volatile("s_waitcnt vmcnt(9)" ::: "memory");
    __builtin_amdgcn_s_barrier();
    comp(it & 3);
    __builtin_amdgcn_s_barrier();
  }
  if constexpr (BMF == 4) asm volatile("s_waitcnt vmcnt(8)" ::: "memory");
  else                    asm volatile("s_waitcnt vmcnt(6)" ::: "memory");
  __builtin_amdgcn_s_barrier(); comp(it & 3); __builtin_amdgcn_s_barrier(); ++it;
  if constexpr (BMF == 4) asm volatile("s_waitcnt vmcnt(4)" ::: "memory");
  else                    asm volatile("s_waitcnt vmcnt(3)" ::: "memory");
  __builtin_amdgcn_s_barrier(); comp(it & 3); __builtin_amdgcn_s_barrier(); ++it;
  asm volatile("s_waitcnt vmcnt(0)" ::: "memory");
  __builtin_amdgcn_s_barrier(); comp(it & 3); __builtin_amdgcn_s_barrier();

#pragma unroll
  for (int mf = 0; mf < BMF; mf++) {
#pragma unroll
    for (int nf = 0; nf < 4; nf++) {
      int col = n0 + wn * 64 + nf * 16 + ll;
      float bv = bias[col];
#pragma unroll
      for (int r = 0; r < 4; r++) {
        int row = m0 + wm * (BMF * 16) + mf * 16 + lg * 4 + r;
        float v = acc[mf][nf][r] + bv;
        if constexpr (EPI == EPI_QKV) {
          if (col < 2048) {          // rope on q,k halves; pair = adjacent lane
            float vp = __shfl_xor(v, 1);
            int sp = row & (SEQ - 1);
            int ip = (col & 63) >> 1;
            float cz = cosb[sp * 32 + ip], sz = sinb[sp * 32 + ip];
            float ov = (col & 1) ? (vp * sz + v * cz) : (v * cz - vp * sz);
            if (col < 1024) ov *= 0.18033688011112042f;   // 0.125*log2e on Q
            v = ov;
          }
          ((unsigned short*)Cout)[(size_t)row * N + col] = f2bf(v);
        } else if constexpr (EPI == EPI_GELU) {
          ((unsigned short*)Cout)[(size_t)row * N + col] = f2bf(gelu_tanh(v));
        } else {
          int bb = row >> 11;
          float g = sst[g_idx * D_MODEL + col] + temb[bb * 6 * D_MODEL + g_idx * D_MODEL + col];
          ((float*)Cout)[(size_t)row * N + col] = v * g + res[(size_t)row * N + col];
        }
      }
    }
  }
}

// ---------------- Flash attention (causal), swapped-operand softmax -----------
__global__ __launch_bounds__(256, 4)
void attn_kernel(const unsigned short* __restrict__ qkv,
                 unsigned short* __restrict__ attn_o) {
  __shared__ unsigned short Klds[2][64 * 64];   // [key][d], 16B-chunk XOR swizzle
  __shared__ unsigned short Vt[2][64 * 64];     // [d][key], 16B-chunk XOR swizzle
  __shared__ unsigned short Plds[4][16 * 64];   // per wave [q][key], XOR swizzle

  const int id = blockIdx.x;
  const int bh = id & 31;
  const int b = bh >> 4, h = bh & 15;
  const int q0 = (id >> 5) * 64;
  const int t = threadIdx.x;
  const int w = t >> 6, l = t & 63;
  const int lg = l >> 4, ll = l & 15;
  const int qw0 = q0 + w * 16;
  const int q_lane = qw0 + ll;

  bf16x8 qf[2];
  {
    const unsigned short* qb = qkv + (size_t)(b * SEQ + q_lane) * 3072 + h * 64;
    qf[0] = *(const bf16x8*)(qb + lg * 8);
    qf[1] = *(const bf16x8*)(qb + 32 + lg * 8);
  }

  const int kp = t & 31, dg = t >> 5;

  f32x4 oacc[4] = {};
  float mrun = -1e30f, lrun = 0.0f;

  {
#pragma unroll
    for (int i = 0; i < 2; i++) {
      int c = i * 256 + t;
      int kr = c >> 3, cc = c & 7;
      gl_lds16(qkv + (size_t)(b * SEQ + kr) * 3072 + 1024 + h * 64 + (cc ^ (kr & 7)) * 8,
               (char*)&Klds[0][0] + c * 16);
    }
    const unsigned short* vp = qkv + (size_t)(b * SEQ + 2 * kp) * 3072 + 2048 + h * 64 + dg * 8;
    union { uint4 u; unsigned short s[8]; } a0, a1;
    a0.u = *(const uint4*)vp;
    a1.u = *(const uint4*)(vp + 3072);
    unsigned int* vt32 = (unsigned int*)&Vt[0][0];
#pragma unroll
    for (int i = 0; i < 8; i++)
      vt32[(dg * 8 + i) * 32 + (((kp >> 2) ^ i) << 2) + (kp & 3)] =
          (unsigned int)a0.s[i] | ((unsigned int)a1.s[i] << 16);
  }
  __syncthreads();

  int buf = 0;
  for (int k0 = 0; k0 <= q0; k0 += 64) {
    const bool has_next = (k0 + 64 <= q0);
    union { uint4 u; unsigned short s[8]; } n0, n1;
    if (has_next) {
#pragma unroll
      for (int i = 0; i < 2; i++) {
        int c = i * 256 + t;
        int kr = c >> 3, cc = c & 7;
        gl_lds16(qkv + (size_t)(b * SEQ + k0 + 64 + kr) * 3072 + 1024 + h * 64 + (cc ^ (kr & 7)) * 8,
                 (char*)&Klds[buf ^ 1][0] + c * 16);
      }
      const unsigned short* vp =
          qkv + (size_t)(b * SEQ + k0 + 64 + 2 * kp) * 3072 + 2048 + h * 64 + dg * 8;
      n0.u = *(const uint4*)vp;
      n1.u = *(const uint4*)(vp + 3072);
    }

    f32x4 s[4] = {};
#pragma unroll
    for (int kk = 0; kk < 2; kk++) {
#pragma unroll
      for (int nf = 0; nf < 4; nf++) {
        int key = nf * 16 + ll;
        int cc = (kk * 4 + lg) ^ (key & 7);
        bf16x8 kf = *(const bf16x8*)((const char*)&Klds[buf][0] + key * 128 + cc * 16);
        s[nf] = __builtin_amdgcn_mfma_f32_16x16x32_bf16(kf, qf[kk], s[nf], 0, 0, 0);
      }
    }
    if (k0 == q0) {
#pragma unroll
      for (int nf = 0; nf < 4; nf++) {
        int key = k0 + nf * 16 + lg * 4;
#pragma unroll
        for (int r = 0; r < 4; r++)
          if (key + r > q_lane) s[nf][r] = -1e30f;
      }
    }
    float mx = -1e30f;
#pragma unroll
    for (int nf = 0; nf < 4; nf++)
#pragma unroll
      for (int r = 0; r < 4; r++) mx = fmaxf(mx, s[nf][r]);
    mx = fmaxf(mx, __shfl_xor(mx, 16));
    mx = fmaxf(mx, __shfl_xor(mx, 32));
    float mnew = fmaxf(mrun, mx);
    float alpha = exp2fast(mrun - mnew);
    mrun = mnew;
    float ps = 0.0f;
#pragma unroll
    for (int nf = 0; nf < 4; nf++)
#pragma unroll
      for (int r = 0; r < 4; r++) {
        float p = exp2fast(s[nf][r] - mnew);
        s[nf][r] = p;
        ps += p;
      }
    ps += __shfl_xor(ps, 16);
    ps += __shfl_xor(ps, 32);
    lrun = lrun * alpha + ps;
#pragma unroll
    for (int nf = 0; nf < 4; nf++)
#pragma unroll
      for (int r = 0; r < 4; r++) oacc[nf][r] *= alpha;

#pragma unroll
    for (int nf = 0; nf < 4; nf++) {
      unsigned int lo = (unsigned int)f2bf(s[nf][0]) | ((unsigned int)f2bf(s[nf][1]) << 16);
      unsigned int hi = (unsigned int)f2bf(s[nf][2]) | ((unsigned int)f2bf(s[nf][3]) << 16);
      int chunk = (nf * 2 + (lg >> 1)) ^ (ll & 7);
      uint2 pv; pv.x = lo; pv.y = hi;
      *(uint2*)((char*)&Plds[w][0] + ll * 128 + chunk * 16 + (lg & 1) * 8) = pv;
    }
    bf16x8 pb[2];
#pragma unroll
    for (int kk = 0; kk < 2; kk++) {
      int pc = (kk * 4 + lg) ^ (ll & 7);
      pb[kk] = *(const bf16x8*)((char*)&Plds[w][0] + ll * 128 + pc * 16);
    }
#pragma unroll
    for (int nf = 0; nf < 4; nf++) {
      int d = nf * 16 + ll;
#pragma unroll
      for (int kk = 0; kk < 2; kk++) {
        int vc = (kk * 4 + lg) ^ (d & 7);
        bf16x8 vb = *(const bf16x8*)((const char*)&Vt[buf][0] + d * 128 + vc * 16);
        oacc[nf] = __builtin_amdgcn_mfma_f32_16x16x32_bf16(vb, pb[kk], oacc[nf], 0, 0, 0);
      }
    }
    if (has_next) {
      unsigned int* vt32 = (unsigned int*)&Vt[buf ^ 1][0];
#pragma unroll
      for (int i = 0; i < 8; i++)
        vt32[(dg * 8 + i) * 32 + (((kp >> 2) ^ i) << 2) + (kp & 3)] =
            (unsigned int)n0.s[i] | ((unsigned int)n1.s[i] << 16);
    }
    __syncthreads();
    buf ^= 1;
  }

  float rl = 1.0f / lrun;
#pragma unroll
  for (int nf = 0; nf < 4; nf++) {
    ushort4 ov;
    ov.x = f2bf(oacc[nf][0] * rl);
    ov.y = f2bf(oacc[nf][1] * rl);
    ov.z = f2bf(oacc[nf][2] * rl);
    ov.w = f2bf(oacc[nf][3] * rl);
    *(ushort4*)(attn_o + (size_t)(b * SEQ + q_lane) * D_MODEL + h * 64 + nf * 16 + lg * 4) = ov;
  }
}

// ------------------------------------------------------------------------------
extern "C" void kernel_launch(void* const* d_in, const int* in_sizes, int n_in,
                              void* d_out, int out_size, void* d_ws, size_t ws_size,
                              hipStream_t stream) {
  const float* hidden_states = (const float*)d_in[0];
  const float* temb     = (const float*)d_in[2];
  const float* rope_cos = (const float*)d_in[3];
  const float* rope_sin = (const float*)d_in[4];
  const float* ln1_w    = (const float*)d_in[5];
  const float* ln1_b    = (const float*)d_in[6];
  const float* ln2_w    = (const float*)d_in[7];
  const float* ln2_b    = (const float*)d_in[8];
  const float* c_attn_w = (const float*)d_in[9];
  const float* c_attn_b = (const float*)d_in[10];
  const float* c_proj_w = (const float*)d_in[11];
  const float* c_proj_b = (const float*)d_in[12];
  const float* fc_w     = (const float*)d_in[13];
  const float* fc_b     = (const float*)d_in[14];
  const float* proj_w   = (const float*)d_in[15];
  const float* proj_b   = (const float*)d_in[16];
  const float* sst      = (const float*)d_in[17];

  char* ws = (char*)d_ws;
  unsigned short* wqkv  = (unsigned short*)(ws + 0);
  unsigned short* wproj = (unsigned short*)(ws + 6291456);
  unsigned short* wfc   = (unsigned short*)(ws + 8388608);
  unsigned short* wp2   = (unsigned short*)(ws + 16777216);
  unsigned short* hln   = (unsigned short*)(ws + 25165824);
  unsigned short* qkvb  = (unsigned short*)(ws + 33554432);
  unsigned short* attno = (unsigned short*)(ws + 58720256);
  unsigned short* h3    = (unsigned short*)(ws + 33554432);   // aliases qkvb+attno
  float*          hidden = (float*)(ws + 67108864);

  dim3 tb(32, 8);
  transpose_convert<<<dim3(3072 / 32, 1024 / 32), tb, 0, stream>>>(c_attn_w, wqkv, 1024, 3072);
  transpose_convert<<<dim3(1024 / 32, 1024 / 32), tb, 0, stream>>>(c_proj_w, wproj, 1024, 1024);
  transpose_convert<<<dim3(4096 / 32, 1024 / 32), tb, 0, stream>>>(fc_w, wfc, 1024, 4096);
  transpose_convert<<<dim3(1024 / 32, 4096 / 32), tb, 0, stream>>>(proj_w, wp2, 4096, 1024);

  ln_mod_kernel<0, 1><<<ROWS, 256, 0, stream>>>(hidden_states, ln1_w, ln1_b, sst, temb, hln);

  gemm_kernel<EPI_QKV, 4><<<dim3(3072 / 128, ROWS / 128), 256, 0, stream>>>(
      hln, wqkv, c_attn_b, qkvb, 3072, 1024, nullptr, nullptr, 0, nullptr, rope_cos, rope_sin);

  attn_kernel<<<dim3(32 * 32), 256, 0, stream>>>(qkvb, attno);

  gemm_kernel<EPI_RES, 2><<<dim3(1024 / 128, ROWS / 64), 256, 0, stream>>>(
      attno, wproj, c_proj_b, hidden, 1024, 1024, sst, temb, 2, hidden_states, nullptr, nullptr);

  ln_mod_kernel<3, 4><<<ROWS, 256, 0, stream>>>(hidden, ln2_w, ln2_b, sst, temb, hln);

  gemm_kernel<EPI_GELU, 4><<<dim3(4096 / 128, ROWS / 128), 256, 0, stream>>>(
      hln, wfc, fc_b, h3, 4096, 1024, nullptr, nullptr, 0, nullptr, nullptr, nullptr);

  gemm_kernel<EPI_FINAL, 2><<<dim3(1024 / 128, ROWS / 64), 256, 0, stream>>>(
      h3, wp2, proj_b, d_out, 1024, 4096, sst, temb, 5, hidden, nullptr, nullptr);
}